// Round 15
// baseline (3296.591 us; speedup 1.0000x reference)
//
#include <hip/hip_runtime.h>
#include <hip/hip_bf16.h>
#include <stdint.h>

#define B_ROWS 16384
#define D_IN   512
#define H_DIM  1024
#define K_TOT  1536
#define NKT    48          // K-tiles of 32

typedef __attribute__((ext_vector_type(8)))  short bf16x8;
typedef __attribute__((ext_vector_type(4)))  float f32x4;
typedef __attribute__((ext_vector_type(4)))  float float4v;
typedef __attribute__((ext_vector_type(8)))  unsigned short u16x8;

__device__ __forceinline__ unsigned short f2bf(float f) {
    uint32_t u = __float_as_uint(f);
    u = (u + 0x7FFFu + ((u >> 16) & 1u)) >> 16;   // RNE
    return (unsigned short)u;
}

// ---------------------------------------------------------------------------
// Ag fragment-linear, 256-row tiles, BK=32 (unchanged):
//   granule g = ((bm*48 + T)*16 + chunk)*64 + lane    (16 B)
//   lane l: row = bm*256 + chunk*16 + (l&15) ; k = T*32 + (l>>4)*8 + j
// ---------------------------------------------------------------------------
__global__ void cvt_A(const float* __restrict__ x, const float* __restrict__ h,
                      unsigned short* __restrict__ Ag) {
    int t     = blockIdx.x * blockDim.x + threadIdx.x;
    int lane  = t & 63;
    int chunk = (t >> 6) & 15;
    int rest  = t >> 10;            // bm*48 + T
    int T     = rest % 48;
    int bm    = rest / 48;
    int row   = bm * 256 + chunk * 16 + (lane & 15);
    int k     = T * 32 + (lane >> 4) * 8;
    const float* src = (k < 512) ? (x + (size_t)row * D_IN + k)
                                 : (h + (size_t)row * H_DIM + (k - 512));
    float4v v0 = *(const float4v*)(src);
    float4v v1 = *(const float4v*)(src + 4);
    u16x8 o;
    o[0] = f2bf(v0[0]); o[1] = f2bf(v0[1]); o[2] = f2bf(v0[2]); o[3] = f2bf(v0[3]);
    o[4] = f2bf(v1[0]); o[5] = f2bf(v1[1]); o[6] = f2bf(v1[2]); o[7] = f2bf(v1[3]);
    *(u16x8*)(Ag + (size_t)t * 8) = o;
}

// ---------------------------------------------------------------------------
// Bg fragment-linear per 1024-col QUAD, gate-interleaved cols (granularity 16):
//   granule g = ((bnq*48 + T)*64 + chunk)*64 + lane    (chunk = 0..63)
//   lane l: c = bnq*1024 + chunk*16 + (l&15) ; k = T*32 + (l>>4)*8 + j
//   gate=(c>>4)&3, h=((c>>6)<<4)|(c&15)
// ---------------------------------------------------------------------------
__global__ void cvt_B(const float* __restrict__ Ui, const float* __restrict__ Uf,
                      const float* __restrict__ Uo, const float* __restrict__ Uc,
                      const float* __restrict__ Wi, const float* __restrict__ Wf,
                      const float* __restrict__ Wo, const float* __restrict__ Wc,
                      unsigned short* __restrict__ Bg) {
    int t     = blockIdx.x * blockDim.x + threadIdx.x;
    int lane  = t & 63;
    int chunk = (t >> 6) & 63;
    int rest  = t >> 12;            // bnq*48 + T
    int T     = rest % 48;
    int bnq   = rest / 48;
    int c     = bnq * 1024 + chunk * 16 + (lane & 15);
    int g     = (c >> 4) & 3;
    int hcol  = ((c >> 6) << 4) | (c & 15);
    int k     = T * 32 + (lane >> 4) * 8;
    const float* up = (g == 0) ? Ui : (g == 1) ? Uf : (g == 2) ? Uo : Uc;
    const float* wp = (g == 0) ? Wi : (g == 1) ? Wf : (g == 2) ? Wo : Wc;
    u16x8 o;
    if (k < 512) {
        const float* s = up + (size_t)k * H_DIM + hcol;
        #pragma unroll
        for (int i = 0; i < 8; ++i) o[i] = f2bf(s[(size_t)i * H_DIM]);
    } else {
        const float* s = wp + (size_t)(k - 512) * H_DIM + hcol;
        #pragma unroll
        for (int i = 0; i < 8; ++i) o[i] = f2bf(s[(size_t)i * H_DIM]);
    }
    *(u16x8*)(Bg + (size_t)t * 8) = o;
}

__global__ void cvt_bias(const float* __restrict__ Uib, const float* __restrict__ Ufb,
                         const float* __restrict__ Uob, const float* __restrict__ Ucb,
                         const float* __restrict__ Wib, const float* __restrict__ Wfb,
                         const float* __restrict__ Wob, const float* __restrict__ Wcb,
                         float* __restrict__ bias) {
    int t = blockIdx.x * blockDim.x + threadIdx.x;
    int g = t >> 10, h = t & 1023;
    const float* ub = (g == 0) ? Uib : (g == 1) ? Ufb : (g == 2) ? Uob : Ucb;
    const float* wb = (g == 0) ? Wib : (g == 1) ? Wfb : (g == 2) ? Wob : Wcb;
    bias[t] = ub[h] + wb[h];
}

// ---------------------------------------------------------------------------
// 256x1024 BLOCK (4 N-tiles fused), 256 blocks = 1/CU, 16x16x32 MFMA, BK=32.
// 8 waves 2Mx4N: wave = 128 rows x 256 cols, acc[8][16] (128 VGPR).
// LDS: 2 slots x 80 KB (A 16 KB chunks 0..15 + B 64 KB chunks 0..63).
// Per tile t: { stage(t+1) -> other slot (10 glds/wave, issued FIRST: full
//   tile of latency slack) ; 8 A-reads ; 16x { 1 B-read ; 8 MFMA } ;
//   s_waitcnt vmcnt(0) ; s_barrier }.
// LDS reads/FLOP HALVED vs all prior rounds (A amortized over 4 N-tiles);
// A L2 traffic / 4. WAR: stage(t+1) targets the slot whose reads completed
// before end-of-(t-1) barrier. RAW: vmcnt(0) gate at end of t.
// ---------------------------------------------------------------------------
__global__ __launch_bounds__(512) void lstm_gemm(
        const unsigned short* __restrict__ Ag, const unsigned short* __restrict__ Bg,
        const float* __restrict__ bias, const float* __restrict__ c_old,
        float* __restrict__ out) {
    __shared__ __align__(1024) char lds[163840];   // 2 slots x 81920

    const int tid = threadIdx.x;
    const int l   = tid & 63;
    const int wv  = tid >> 6;
    const int wm  = wv >> 2;      // 0..1  (128-row slice)
    const int wn  = wv & 3;       // 0..3  (256-col slice)

    // XCD swizzle: 256 blocks, bnq per XCD-pair, bm within
    const int orig = blockIdx.x;              // 0..255
    const int xcd  = orig & 7;
    const int jj   = orig >> 3;               // 0..31
    const int bm   = (xcd & 1) * 32 + jj;     // 0..63
    const int bnq  = xcd >> 1;                // 0..3

    // staging sources
    const unsigned short* aSrc = Ag + (size_t)bm * 48 * 8192 + (size_t)(2 * wv) * 512 + l * 8;
    const unsigned short* bSrc = Bg + (size_t)bnq * 48 * 32768 + (size_t)(8 * wv) * 512 + l * 8;

    // LDS read lane offsets
    const int aRd = wm * 8192 + l * 16;             // + m*1024, m=0..7
    const int bRd = 16384 + wn * 16384 + l * 16;    // + nf*1024, nf=0..15

#define GLDS(SRC, DST) __builtin_amdgcn_global_load_lds(                            \
        (const __attribute__((address_space(1))) void*)(SRC),                       \
        (__attribute__((address_space(3))) void*)(DST), 16, 0, 0)

#define STAGE(T, SLOTBASE) do {                                                     \
    const unsigned short* _sa = aSrc + (size_t)(T) * 8192;                          \
    const unsigned short* _sb = bSrc + (size_t)(T) * 32768;                         \
    char* _da = (char*)lds + (SLOTBASE) + 2 * wv * 1024;                            \
    char* _db = (char*)lds + (SLOTBASE) + 16384 + 8 * wv * 1024;                    \
    GLDS(_sa, _da);          GLDS(_sa + 512, _da + 1024);                           \
    _Pragma("unroll") for (int q = 0; q < 8; ++q)                                   \
        GLDS(_sb + q * 512, _db + q * 1024);                                        \
} while (0)

    f32x4 acc[8][16] = {};

#define TILE(T, SLOTBASE, OSLOTBASE) do {                                           \
    int _tn = (T) + 1; if (_tn >= NKT) _tn = 0;      /* wrap: dummy, never read */  \
    STAGE(_tn, OSLOTBASE);                                                          \
    const char* _Ab = (const char*)lds + (SLOTBASE) + aRd;                          \
    const char* _Bb = (const char*)lds + (SLOTBASE) + bRd;                          \
    bf16x8 aF[8];                                                                   \
    _Pragma("unroll") for (int m = 0; m < 8; ++m)                                   \
        aF[m] = *(const bf16x8*)(_Ab + m * 1024);                                   \
    _Pragma("unroll") for (int nf = 0; nf < 16; ++nf) {                             \
        bf16x8 bF = *(const bf16x8*)(_Bb + nf * 1024);                              \
        _Pragma("unroll") for (int m = 0; m < 8; ++m)                               \
            acc[m][nf] = __builtin_amdgcn_mfma_f32_16x16x32_bf16(                   \
                aF[m], bF, acc[m][nf], 0, 0, 0);                                    \
    }                                                                               \
    asm volatile("s_waitcnt vmcnt(0)");                                             \
    __builtin_amdgcn_s_barrier();                                                   \
} while (0)

    // ---- prologue: stage tile 0 -> slot 0 ----
    STAGE(0, 0);
    asm volatile("s_waitcnt vmcnt(0)");
    __builtin_amdgcn_s_barrier();

    // ---- main loop: 24 iters x 2 tiles (slots ping-pong, constant bases) ----
    #pragma unroll 1
    for (int i = 0; i < 24; ++i) {
        TILE(2 * i,     0,     81920);
        TILE(2 * i + 1, 81920, 0);
    }

    // ---- fused LSTM epilogue: 4 h-groups x 4 gates in-lane ----
    const int l15 = l & 15;
    const int hbase = bnq * 256 + wn * 64 + l15;

    #pragma unroll
    for (int hg = 0; hg < 4; ++hg) {
        const int hh = hbase + hg * 16;
        const float bi  = bias[hh];
        const float bff = bias[1024 + hh];
        const float bo  = bias[2048 + hh];
        const float bc  = bias[3072 + hh];
        #pragma unroll
        for (int m = 0; m < 8; ++m) {
            const int rb = bm * 256 + wm * 128 + m * 16 + ((l >> 4) * 4);
            #pragma unroll
            for (int j = 0; j < 4; ++j) {
                const int r = rb + j;
                float iv = acc[m][hg * 4 + 0][j] + bi;
                float fv = acc[m][hg * 4 + 1][j] + bff;
                float ov = acc[m][hg * 4 + 2][j] + bo;
                float gv = acc[m][hg * 4 + 3][j] + bc;
                float it = 1.f / (1.f + __expf(-iv));
                float ft = 1.f / (1.f + __expf(-fv));
                float ot = 1.f / (1.f + __expf(-ov));
                float gt = 1.f - 2.f / (1.f + __expf(2.f * gv));
                float co = c_old[(size_t)r * H_DIM + hh];
                float cn = it * gt + ft * co;
                float th = 1.f - 2.f / (1.f + __expf(2.f * cn));
                out[(size_t)r * H_DIM + hh] = ot * th;                        // h_new
                out[(size_t)B_ROWS * H_DIM + (size_t)r * H_DIM + hh] = cn;    // c
            }
        }
    }
#undef TILE
#undef STAGE
#undef GLDS
}

extern "C" void kernel_launch(void* const* d_in, const int* in_sizes, int n_in,
                              void* d_out, int out_size, void* d_ws, size_t ws_size,
                              hipStream_t stream) {
    const float* x  = (const float*)d_in[0];
    const float* h0 = (const float*)d_in[1];
    const float* c0 = (const float*)d_in[2];
    const float* Uw[4] = {(const float*)d_in[3],  (const float*)d_in[5],
                          (const float*)d_in[7],  (const float*)d_in[9]};
    const float* Ub[4] = {(const float*)d_in[4],  (const float*)d_in[6],
                          (const float*)d_in[8],  (const float*)d_in[10]};
    const float* Ww[4] = {(const float*)d_in[11], (const float*)d_in[13],
                          (const float*)d_in[15], (const float*)d_in[17]};
    const float* Wb[4] = {(const float*)d_in[12], (const float*)d_in[14],
                          (const float*)d_in[16], (const float*)d_in[18]};

    unsigned short* Ag = (unsigned short*)d_ws;                 // 48 MiB
    unsigned short* Bg = Ag + (size_t)B_ROWS * K_TOT;           // 12 MiB
    float* bias        = (float*)(Bg + (size_t)4096 * K_TOT);   // 16 KiB
    float* out         = (float*)d_out;

    cvt_A<<<12288, 256, 0, stream>>>(x, h0, Ag);
    cvt_B<<<3072, 256, 0, stream>>>(Uw[0], Uw[1], Uw[2], Uw[3],
                                    Ww[0], Ww[1], Ww[2], Ww[3], Bg);
    cvt_bias<<<16, 256, 0, stream>>>(Ub[0], Ub[1], Ub[2], Ub[3],
                                     Wb[0], Wb[1], Wb[2], Wb[3], bias);
    lstm_gemm<<<256, 512, 0, stream>>>(Ag, Bg, bias, c0, out);
}

// Round 16
// 257.180 us; speedup vs baseline: 12.8182x; 12.8182x over previous
//
#include <hip/hip_runtime.h>
#include <hip/hip_bf16.h>
#include <stdint.h>

#define B_ROWS 16384
#define D_IN   512
#define H_DIM  1024
#define K_TOT  1536
#define NT64   24          // K-tiles of 64

typedef __attribute__((ext_vector_type(8)))  short bf16x8;
typedef __attribute__((ext_vector_type(4)))  float f32x4;
typedef __attribute__((ext_vector_type(4)))  float float4v;
typedef __attribute__((ext_vector_type(8)))  unsigned short u16x8;

__device__ __forceinline__ unsigned short f2bf(float f) {
    uint32_t u = __float_as_uint(f);
    u = (u + 0x7FFFu + ((u >> 16) & 1u)) >> 16;   // RNE
    return (unsigned short)u;
}

// ---------------------------------------------------------------------------
// Ag fragment-linear, 256-row tiles, BK=64 split in k-halves:
//   granule g = (((bm*24 + T)*2 + kh)*16 + chunk)*64 + lane   (16 B)
//   lane l: row = bm*256 + chunk*16 + (l&15) ; k = T*64 + kh*32 + (l>>4)*8 + j
// ---------------------------------------------------------------------------
__global__ void cvt_A(const float* __restrict__ x, const float* __restrict__ h,
                      unsigned short* __restrict__ Ag) {
    int t     = blockIdx.x * blockDim.x + threadIdx.x;
    int lane  = t & 63;
    int chunk = (t >> 6) & 15;
    int kh    = (t >> 10) & 1;
    int rest  = t >> 11;            // bm*24 + T
    int T     = rest % 24;
    int bm    = rest / 24;
    int row   = bm * 256 + chunk * 16 + (lane & 15);
    int k     = T * 64 + kh * 32 + (lane >> 4) * 8;
    const float* src = (k < 512) ? (x + (size_t)row * D_IN + k)
                                 : (h + (size_t)row * H_DIM + (k - 512));
    float4v v0 = *(const float4v*)(src);
    float4v v1 = *(const float4v*)(src + 4);
    u16x8 o;
    o[0] = f2bf(v0[0]); o[1] = f2bf(v0[1]); o[2] = f2bf(v0[2]); o[3] = f2bf(v0[3]);
    o[4] = f2bf(v1[0]); o[5] = f2bf(v1[1]); o[6] = f2bf(v1[2]); o[7] = f2bf(v1[3]);
    *(u16x8*)(Ag + (size_t)t * 8) = o;
}

// ---------------------------------------------------------------------------
// Bg fragment-linear, gate-interleaved cols (granularity 16, R1-proven):
//   col c = (h>>4)*64 + gate*16 + (h&15)
//   granule g = (((bn*24 + T)*2 + kh)*16 + chunk)*64 + lane
//   lane l: c = bn*256 + chunk*16 + (l&15) ; k = T*64 + kh*32 + (l>>4)*8 + j
// ---------------------------------------------------------------------------
__global__ void cvt_B(const float* __restrict__ Ui, const float* __restrict__ Uf,
                      const float* __restrict__ Uo, const float* __restrict__ Uc,
                      const float* __restrict__ Wi, const float* __restrict__ Wf,
                      const float* __restrict__ Wo, const float* __restrict__ Wc,
                      unsigned short* __restrict__ Bg) {
    int t     = blockIdx.x * blockDim.x + threadIdx.x;
    int lane  = t & 63;
    int chunk = (t >> 6) & 15;
    int kh    = (t >> 10) & 1;
    int rest  = t >> 11;            // bn*24 + T
    int T     = rest % 24;
    int bn    = rest / 24;
    int c     = bn * 256 + chunk * 16 + (lane & 15);
    int g     = (c >> 4) & 3;
    int hcol  = ((c >> 6) << 4) | (c & 15);
    int k     = T * 64 + kh * 32 + (lane >> 4) * 8;
    const float* up = (g == 0) ? Ui : (g == 1) ? Uf : (g == 2) ? Uo : Uc;
    const float* wp = (g == 0) ? Wi : (g == 1) ? Wf : (g == 2) ? Wo : Wc;
    u16x8 o;
    if (k < 512) {
        const float* s = up + (size_t)k * H_DIM + hcol;
        #pragma unroll
        for (int i = 0; i < 8; ++i) o[i] = f2bf(s[(size_t)i * H_DIM]);
    } else {
        const float* s = wp + (size_t)(k - 512) * H_DIM + hcol;
        #pragma unroll
        for (int i = 0; i < 8; ++i) o[i] = f2bf(s[(size_t)i * H_DIM]);
    }
    *(u16x8*)(Bg + (size_t)t * 8) = o;
}

__global__ void cvt_bias(const float* __restrict__ Uib, const float* __restrict__ Ufb,
                         const float* __restrict__ Uob, const float* __restrict__ Ucb,
                         const float* __restrict__ Wib, const float* __restrict__ Wfb,
                         const float* __restrict__ Wob, const float* __restrict__ Wcb,
                         float* __restrict__ bias) {
    int t = blockIdx.x * blockDim.x + threadIdx.x;
    int g = t >> 10, h = t & 1023;
    const float* ub = (g == 0) ? Uib : (g == 1) ? Ufb : (g == 2) ? Uob : Ucb;
    const float* wb = (g == 0) ? Wib : (g == 1) ? Wfb : (g == 2) ? Wob : Wcb;
    bias[t] = ub[h] + wb[h];
}

// ---------------------------------------------------------------------------
// m201-faithful 256x256 8-phase GEMM, BK=64, 512 thr (8 waves 2Mx4N),
// 16x16x32 MFMA, per-wave 128x64 (acc[8][4]).  [BEST MEASURED: 256.2 us]
// Phases = (K-half x M-half) per tile; q0 reads 4A+4B, q1 reads 4A (B in regs).
// LDS 128 KB: buf(2) x mat(2) x khalf(2) x 16 KB, fragment-linear (0 conflicts).
// Stages (1 region/phase, after the target's last-read barrier):
//   ph1:A(t1).k1->b1  ph2:B(t1).k1->b1  ph3:A(t2).k0->b0  ph4:B(t2).k0->b0
//   ph5:A(t2).k1->b0  ph6:B(t2).k1->b0  ph7:A(t3).k0->b1  ph8:B(t3).k0->b1
// Gates: vmcnt(4) at ph4 and ph8 ONLY. Never vmcnt(0) in the loop.
// Phase body: {reads; stage; barrier; lgkmcnt(0); sched_barrier; setprio(1);
// 16 MFMA; setprio(0); barrier(+gate)}.
// ---------------------------------------------------------------------------
__global__ __launch_bounds__(512) void lstm_gemm(
        const unsigned short* __restrict__ Ag, const unsigned short* __restrict__ Bg,
        const float* __restrict__ bias, const float* __restrict__ c_old,
        float* __restrict__ out) {
    __shared__ __align__(1024) char lds[131072];

    const int tid = threadIdx.x;
    const int l   = tid & 63;
    const int wv  = tid >> 6;
    const int wm  = wv >> 2;      // 0..1  (128-row slice)
    const int wn  = wv & 3;       // 0..3  (64-col slice)

    // XCD swizzle: per XCD 8bm x 4bn
    const int orig = blockIdx.x;              // 1024 blocks
    const int xcd  = orig & 7;
    const int jj   = orig >> 3;
    const int bn   = (xcd & 3) * 4 + (jj & 3);     // 0..15
    const int bm   = (xcd >> 2) * 32 + (jj >> 2);  // 0..63

    // staging sources: region (T,kh) at +((T*2+kh)*8192) elems; thread granule
    const unsigned short* aSrc = Ag + (size_t)bm * 24 * 16384 + tid * 8;
    const unsigned short* bSrc = Bg + (size_t)bn * 24 * 16384 + tid * 8;

    // LDS read lane offsets
    const int aRd = wm * 8192 + l * 16;     // + (q*4+m)*1024
    const int bRd = wn * 4096 + l * 16;     // + n*1024

#define GLDS(SRC, DST) __builtin_amdgcn_global_load_lds(                            \
        (const __attribute__((address_space(1))) void*)(SRC),                       \
        (__attribute__((address_space(3))) void*)(DST), 16, 0, 0)

#define STAGE(MAT, T, KH, BUF) do {                                                 \
    const unsigned short* _s = ((MAT) ? bSrc : aSrc) + (size_t)((T) * 2 + (KH)) * 8192; \
    char* _d = (char*)lds + (BUF) * 65536 + (MAT) * 32768 + (KH) * 16384 + wv * 1024;   \
    GLDS(_s, _d);  GLDS(_s + 4096, _d + 8192);                                      \
} while (0)

    f32x4 acc[8][4] = {};
    bf16x8 bPers[4];

#define PHASE(BUF, KH, Q, RB, SM, ST, SKH, SBUF, GATE) do {                         \
    const char* _Ab = (const char*)lds + (BUF) * 65536 + (KH) * 16384 + aRd;        \
    bf16x8 aF[4];                                                                   \
    _Pragma("unroll") for (int m = 0; m < 4; ++m)                                   \
        aF[m] = *(const bf16x8*)(_Ab + ((Q) * 4 + m) * 1024);                       \
    if (RB) {                                                                       \
        const char* _Bb = (const char*)lds + (BUF) * 65536 + 32768 + (KH) * 16384 + bRd; \
        _Pragma("unroll") for (int n = 0; n < 4; ++n)                               \
            bPers[n] = *(const bf16x8*)(_Bb + n * 1024);                            \
    }                                                                               \
    STAGE(SM, ST, SKH, SBUF);                                                       \
    __builtin_amdgcn_s_barrier();                                                   \
    asm volatile("s_waitcnt lgkmcnt(0)" ::: "memory");                              \
    __builtin_amdgcn_sched_barrier(0);                                              \
    __builtin_amdgcn_s_setprio(1);                                                  \
    _Pragma("unroll") for (int m = 0; m < 4; ++m)                                   \
        _Pragma("unroll") for (int n = 0; n < 4; ++n)                               \
            acc[(Q) * 4 + m][n] = __builtin_amdgcn_mfma_f32_16x16x32_bf16(          \
                aF[m], bPers[n], acc[(Q) * 4 + m][n], 0, 0, 0);                     \
    __builtin_amdgcn_s_setprio(0);                                                  \
    if (GATE) { asm volatile("s_waitcnt vmcnt(4)\ns_barrier" ::: "memory"); }       \
    else      { asm volatile("s_barrier" ::: "memory"); }                           \
} while (0)

    // ---- prologue: T0 fully + T1.k0 (12 loads); vmcnt(4) retires T0 ----
    STAGE(0, 0, 0, 0); STAGE(1, 0, 0, 0);
    STAGE(0, 0, 1, 0); STAGE(1, 0, 1, 0);
    STAGE(0, 1, 0, 1); STAGE(1, 1, 0, 1);
    asm volatile("s_waitcnt vmcnt(4)\ns_barrier" ::: "memory");

    // ---- main loop: 12 iterations, tiles 2i (buf0) and 2i+1 (buf1) ----
    #pragma unroll 1
    for (int i = 0; i < 12; ++i) {
        const int t1 = 2 * i + 1;
        int t2 = 2 * i + 2; if (t2 >= NT64) t2 -= NT64;   // wrap: staged, never read
        int t3 = 2 * i + 3; if (t3 >= NT64) t3 -= NT64;
        PHASE(0, 0, 0, 1,  0, t1, 1, 1,  0);   // T0.k0.q0 ; stage A(t1).k1->b1
        PHASE(0, 0, 1, 0,  1, t1, 1, 1,  0);   // T0.k0.q1 ; stage B(t1).k1->b1
        PHASE(0, 1, 0, 1,  0, t2, 0, 0,  0);   // T0.k1.q0 ; stage A(t2).k0->b0
        PHASE(0, 1, 1, 0,  1, t2, 0, 0,  1);   // T0.k1.q1 ; stage B(t2).k0 ; GATE
        PHASE(1, 0, 0, 1,  0, t2, 1, 0,  0);   // T1.k0.q0 ; stage A(t2).k1->b0
        PHASE(1, 0, 1, 0,  1, t2, 1, 0,  0);   // T1.k0.q1 ; stage B(t2).k1->b0
        PHASE(1, 1, 0, 1,  0, t3, 0, 1,  0);   // T1.k1.q0 ; stage A(t3).k0->b1
        PHASE(1, 1, 1, 0,  1, t3, 0, 1,  1);   // T1.k1.q1 ; stage B(t3).k0 ; GATE
    }
    asm volatile("s_waitcnt vmcnt(0)" ::: "memory");   // drain wrapped stagings

    // ---- fused LSTM epilogue: gate = n (in-lane), hh = (bn*4+wn)*16 + col ----
    const int hh  = (bn * 4 + wn) * 16 + (l & 15);
    const float bi  = bias[hh];
    const float bff = bias[1024 + hh];
    const float bo  = bias[2048 + hh];
    const float bc  = bias[3072 + hh];

    #pragma unroll
    for (int a = 0; a < 8; ++a) {
        const int rb = bm * 256 + wm * 128 + (a >> 2) * 64 + (a & 3) * 16 + ((l >> 4) * 4);
        #pragma unroll
        for (int j = 0; j < 4; ++j) {
            const int r = rb + j;
            float iv = acc[a][0][j] + bi;
            float fv = acc[a][1][j] + bff;
            float ov = acc[a][2][j] + bo;
            float gv = acc[a][3][j] + bc;
            float it = 1.f / (1.f + __expf(-iv));
            float ft = 1.f / (1.f + __expf(-fv));
            float ot = 1.f / (1.f + __expf(-ov));
            float gt = 1.f - 2.f / (1.f + __expf(2.f * gv));
            float co = c_old[(size_t)r * H_DIM + hh];
            float cn = it * gt + ft * co;
            float th = 1.f - 2.f / (1.f + __expf(2.f * cn));
            out[(size_t)r * H_DIM + hh] = ot * th;                          // h_new
            out[(size_t)B_ROWS * H_DIM + (size_t)r * H_DIM + hh] = cn;      // c
        }
    }
#undef PHASE
#undef STAGE
#undef GLDS
}

extern "C" void kernel_launch(void* const* d_in, const int* in_sizes, int n_in,
                              void* d_out, int out_size, void* d_ws, size_t ws_size,
                              hipStream_t stream) {
    const float* x  = (const float*)d_in[0];
    const float* h0 = (const float*)d_in[1];
    const float* c0 = (const float*)d_in[2];
    const float* Uw[4] = {(const float*)d_in[3],  (const float*)d_in[5],
                          (const float*)d_in[7],  (const float*)d_in[9]};
    const float* Ub[4] = {(const float*)d_in[4],  (const float*)d_in[6],
                          (const float*)d_in[8],  (const float*)d_in[10]};
    const float* Ww[4] = {(const float*)d_in[11], (const float*)d_in[13],
                          (const float*)d_in[15], (const float*)d_in[17]};
    const float* Wb[4] = {(const float*)d_in[12], (const float*)d_in[14],
                          (const float*)d_in[16], (const float*)d_in[18]};

    unsigned short* Ag = (unsigned short*)d_ws;                 // 48 MiB
    unsigned short* Bg = Ag + (size_t)B_ROWS * K_TOT;           // 12 MiB
    float* bias        = (float*)(Bg + (size_t)4096 * K_TOT);   // 16 KiB
    float* out         = (float*)d_out;

    cvt_A<<<12288, 256, 0, stream>>>(x, h0, Ag);
    cvt_B<<<3072, 256, 0, stream>>>(Uw[0], Uw[1], Uw[2], Uw[3],
                                    Ww[0], Ww[1], Ww[2], Ww[3], Bg);
    cvt_bias<<<16, 256, 0, stream>>>(Ub[0], Ub[1], Ub[2], Ub[3],
                                     Wb[0], Wb[1], Wb[2], Wb[3], bias);
    lstm_gemm<<<1024, 512, 0, stream>>>(Ag, Bg, bias, c0, out);
}

// Round 17
// 252.279 us; speedup vs baseline: 13.0672x; 1.0194x over previous
//
#include <hip/hip_runtime.h>
#include <hip/hip_bf16.h>
#include <stdint.h>

#define B_ROWS 16384
#define D_IN   512
#define H_DIM  1024
#define K_TOT  1536
#define NT64   24          // K-tiles of 64

typedef __attribute__((ext_vector_type(8)))  short bf16x8;
typedef __attribute__((ext_vector_type(4)))  float f32x4;
typedef __attribute__((ext_vector_type(4)))  float float4v;
typedef __attribute__((ext_vector_type(8)))  unsigned short u16x8;

__device__ __forceinline__ unsigned short f2bf(float f) {
    uint32_t u = __float_as_uint(f);
    u = (u + 0x7FFFu + ((u >> 16) & 1u)) >> 16;   // RNE
    return (unsigned short)u;
}

// ---------------------------------------------------------------------------
// FUSED prep: blocks [0,12288) = A-convert, [12288,15360) = B-convert,
// [15360,15376) = bias. All three are independent -> run concurrently in one
// dispatch instead of 3 serialized launches.
//
// Ag fragment-linear, 256-row tiles, BK=64 split in k-halves:
//   granule g = (((bm*24 + T)*2 + kh)*16 + chunk)*64 + lane   (16 B)
//   lane l: row = bm*256 + chunk*16 + (l&15) ; k = T*64 + kh*32 + (l>>4)*8 + j
// Bg fragment-linear, gate-interleaved cols (granularity 16, R1-proven):
//   col c = (h>>4)*64 + gate*16 + (h&15)
//   granule g = (((bn*24 + T)*2 + kh)*16 + chunk)*64 + lane
// ---------------------------------------------------------------------------
__global__ void cvt_all(
        const float* __restrict__ x,  const float* __restrict__ h,
        const float* __restrict__ Ui, const float* __restrict__ Uf,
        const float* __restrict__ Uo, const float* __restrict__ Uc,
        const float* __restrict__ Wi, const float* __restrict__ Wf,
        const float* __restrict__ Wo, const float* __restrict__ Wc,
        const float* __restrict__ Uib, const float* __restrict__ Ufb,
        const float* __restrict__ Uob, const float* __restrict__ Ucb,
        const float* __restrict__ Wib, const float* __restrict__ Wfb,
        const float* __restrict__ Wob, const float* __restrict__ Wcb,
        unsigned short* __restrict__ Ag, unsigned short* __restrict__ Bg,
        float* __restrict__ bias) {
    const int bid = blockIdx.x;
    if (bid < 12288) {
        // ---- A-convert ----
        int t     = bid * 256 + threadIdx.x;
        int lane  = t & 63;
        int chunk = (t >> 6) & 15;
        int kh    = (t >> 10) & 1;
        int rest  = t >> 11;            // bm*24 + T
        int T     = rest % 24;
        int bm    = rest / 24;
        int row   = bm * 256 + chunk * 16 + (lane & 15);
        int k     = T * 64 + kh * 32 + (lane >> 4) * 8;
        const float* src = (k < 512) ? (x + (size_t)row * D_IN + k)
                                     : (h + (size_t)row * H_DIM + (k - 512));
        float4v v0 = *(const float4v*)(src);
        float4v v1 = *(const float4v*)(src + 4);
        u16x8 o;
        o[0] = f2bf(v0[0]); o[1] = f2bf(v0[1]); o[2] = f2bf(v0[2]); o[3] = f2bf(v0[3]);
        o[4] = f2bf(v1[0]); o[5] = f2bf(v1[1]); o[6] = f2bf(v1[2]); o[7] = f2bf(v1[3]);
        *(u16x8*)(Ag + (size_t)t * 8) = o;
    } else if (bid < 15360) {
        // ---- B-convert ----
        int t     = (bid - 12288) * 256 + threadIdx.x;
        int lane  = t & 63;
        int chunk = (t >> 6) & 15;
        int kh    = (t >> 10) & 1;
        int rest  = t >> 11;            // bn*24 + T
        int T     = rest % 24;
        int bn    = rest / 24;
        int c     = bn * 256 + chunk * 16 + (lane & 15);
        int g     = (c >> 4) & 3;
        int hcol  = ((c >> 6) << 4) | (c & 15);
        int k     = T * 64 + kh * 32 + (lane >> 4) * 8;
        const float* up = (g == 0) ? Ui : (g == 1) ? Uf : (g == 2) ? Uo : Uc;
        const float* wp = (g == 0) ? Wi : (g == 1) ? Wf : (g == 2) ? Wo : Wc;
        u16x8 o;
        if (k < 512) {
            const float* s = up + (size_t)k * H_DIM + hcol;
            #pragma unroll
            for (int i = 0; i < 8; ++i) o[i] = f2bf(s[(size_t)i * H_DIM]);
        } else {
            const float* s = wp + (size_t)(k - 512) * H_DIM + hcol;
            #pragma unroll
            for (int i = 0; i < 8; ++i) o[i] = f2bf(s[(size_t)i * H_DIM]);
        }
        *(u16x8*)(Bg + (size_t)t * 8) = o;
    } else {
        // ---- bias ----
        int t = (bid - 15360) * 256 + threadIdx.x;
        int g = t >> 10, hh = t & 1023;
        const float* ub = (g == 0) ? Uib : (g == 1) ? Ufb : (g == 2) ? Uob : Ucb;
        const float* wb = (g == 0) ? Wib : (g == 1) ? Wfb : (g == 2) ? Wob : Wcb;
        bias[t] = ub[hh] + wb[hh];
    }
}

// ---------------------------------------------------------------------------
// m201-faithful 256x256 8-phase GEMM, BK=64, 512 thr (8 waves 2Mx4N),
// 16x16x32 MFMA, per-wave 128x64 (acc[8][4]).  [BEST MEASURED: 256.2 us]
// Phases = (K-half x M-half) per tile; q0 reads 4A+4B, q1 reads 4A (B in regs).
// LDS 128 KB: buf(2) x mat(2) x khalf(2) x 16 KB, fragment-linear (0 conflicts).
// Stages: ph1:A(t1).k1  ph2:B(t1).k1  ph3:A(t2).k0  ph4:B(t2).k0
//         ph5:A(t2).k1  ph6:B(t2).k1  ph7:A(t3).k0  ph8:B(t3).k0
// Gates: vmcnt(4) at ph4 and ph8 ONLY. Never vmcnt(0) in the loop.
// NEW vs R16: c_old prefetched into registers BEFORE the final drain, so the
// 32 scattered 4B loads overlap the wrapped-staging drain instead of
// serializing at block end (4 blocks/CU x ~1k cyc saved).
// ---------------------------------------------------------------------------
__global__ __launch_bounds__(512) void lstm_gemm(
        const unsigned short* __restrict__ Ag, const unsigned short* __restrict__ Bg,
        const float* __restrict__ bias, const float* __restrict__ c_old,
        float* __restrict__ out) {
    __shared__ __align__(1024) char lds[131072];

    const int tid = threadIdx.x;
    const int l   = tid & 63;
    const int wv  = tid >> 6;
    const int wm  = wv >> 2;      // 0..1  (128-row slice)
    const int wn  = wv & 3;       // 0..3  (64-col slice)

    // XCD swizzle: per XCD 8bm x 4bn
    const int orig = blockIdx.x;              // 1024 blocks
    const int xcd  = orig & 7;
    const int jj   = orig >> 3;
    const int bn   = (xcd & 3) * 4 + (jj & 3);     // 0..15
    const int bm   = (xcd >> 2) * 32 + (jj >> 2);  // 0..63

    // staging sources: region (T,kh) at +((T*2+kh)*8192) elems; thread granule
    const unsigned short* aSrc = Ag + (size_t)bm * 24 * 16384 + tid * 8;
    const unsigned short* bSrc = Bg + (size_t)bn * 24 * 16384 + tid * 8;

    // LDS read lane offsets
    const int aRd = wm * 8192 + l * 16;     // + (q*4+m)*1024
    const int bRd = wn * 4096 + l * 16;     // + n*1024

#define GLDS(SRC, DST) __builtin_amdgcn_global_load_lds(                            \
        (const __attribute__((address_space(1))) void*)(SRC),                       \
        (__attribute__((address_space(3))) void*)(DST), 16, 0, 0)

#define STAGE(MAT, T, KH, BUF) do {                                                 \
    const unsigned short* _s = ((MAT) ? bSrc : aSrc) + (size_t)((T) * 2 + (KH)) * 8192; \
    char* _d = (char*)lds + (BUF) * 65536 + (MAT) * 32768 + (KH) * 16384 + wv * 1024;   \
    GLDS(_s, _d);  GLDS(_s + 4096, _d + 8192);                                      \
} while (0)

    f32x4 acc[8][4] = {};
    bf16x8 bPers[4];

#define PHASE(BUF, KH, Q, RB, SM, ST, SKH, SBUF, GATE) do {                         \
    const char* _Ab = (const char*)lds + (BUF) * 65536 + (KH) * 16384 + aRd;        \
    bf16x8 aF[4];                                                                   \
    _Pragma("unroll") for (int m = 0; m < 4; ++m)                                   \
        aF[m] = *(const bf16x8*)(_Ab + ((Q) * 4 + m) * 1024);                       \
    if (RB) {                                                                       \
        const char* _Bb = (const char*)lds + (BUF) * 65536 + 32768 + (KH) * 16384 + bRd; \
        _Pragma("unroll") for (int n = 0; n < 4; ++n)                               \
            bPers[n] = *(const bf16x8*)(_Bb + n * 1024);                            \
    }                                                                               \
    STAGE(SM, ST, SKH, SBUF);                                                       \
    __builtin_amdgcn_s_barrier();                                                   \
    asm volatile("s_waitcnt lgkmcnt(0)" ::: "memory");                              \
    __builtin_amdgcn_sched_barrier(0);                                              \
    __builtin_amdgcn_s_setprio(1);                                                  \
    _Pragma("unroll") for (int m = 0; m < 4; ++m)                                   \
        _Pragma("unroll") for (int n = 0; n < 4; ++n)                               \
            acc[(Q) * 4 + m][n] = __builtin_amdgcn_mfma_f32_16x16x32_bf16(          \
                aF[m], bPers[n], acc[(Q) * 4 + m][n], 0, 0, 0);                     \
    __builtin_amdgcn_s_setprio(0);                                                  \
    if (GATE) { asm volatile("s_waitcnt vmcnt(4)\ns_barrier" ::: "memory"); }       \
    else      { asm volatile("s_barrier" ::: "memory"); }                           \
} while (0)

    // ---- prologue: T0 fully + T1.k0 (12 loads); vmcnt(4) retires T0 ----
    STAGE(0, 0, 0, 0); STAGE(1, 0, 0, 0);
    STAGE(0, 0, 1, 0); STAGE(1, 0, 1, 0);
    STAGE(0, 1, 0, 1); STAGE(1, 1, 0, 1);
    asm volatile("s_waitcnt vmcnt(4)\ns_barrier" ::: "memory");

    // ---- main loop: 12 iterations, tiles 2i (buf0) and 2i+1 (buf1) ----
    #pragma unroll 1
    for (int i = 0; i < 12; ++i) {
        const int t1 = 2 * i + 1;
        int t2 = 2 * i + 2; if (t2 >= NT64) t2 -= NT64;   // wrap: staged, never read
        int t3 = 2 * i + 3; if (t3 >= NT64) t3 -= NT64;
        PHASE(0, 0, 0, 1,  0, t1, 1, 1,  0);   // T0.k0.q0 ; stage A(t1).k1->b1
        PHASE(0, 0, 1, 0,  1, t1, 1, 1,  0);   // T0.k0.q1 ; stage B(t1).k1->b1
        PHASE(0, 1, 0, 1,  0, t2, 0, 0,  0);   // T0.k1.q0 ; stage A(t2).k0->b0
        PHASE(0, 1, 1, 0,  1, t2, 0, 0,  1);   // T0.k1.q1 ; stage B(t2).k0 ; GATE
        PHASE(1, 0, 0, 1,  0, t2, 1, 0,  0);   // T1.k0.q0 ; stage A(t2).k1->b0
        PHASE(1, 0, 1, 0,  1, t2, 1, 0,  0);   // T1.k0.q1 ; stage B(t2).k1->b0
        PHASE(1, 1, 0, 1,  0, t3, 0, 1,  0);   // T1.k1.q0 ; stage A(t3).k0->b1
        PHASE(1, 1, 1, 0,  1, t3, 0, 1,  1);   // T1.k1.q1 ; stage B(t3).k0 ; GATE
    }

    // ---- c_old prefetch: issue BEFORE the drain so the 32 scattered loads
    //      overlap the wrapped-staging drain instead of the epilogue ----
    const int hh  = (bn * 4 + wn) * 16 + (l & 15);
    float cv[8][4];
    #pragma unroll
    for (int a = 0; a < 8; ++a) {
        const int rb = bm * 256 + wm * 128 + (a >> 2) * 64 + (a & 3) * 16 + ((l >> 4) * 4);
        #pragma unroll
        for (int j = 0; j < 4; ++j)
            cv[a][j] = c_old[(size_t)(rb + j) * H_DIM + hh];
    }
    asm volatile("s_waitcnt vmcnt(0)" ::: "memory");   // drain stagings + c_old

    // ---- fused LSTM epilogue: gate = n (in-lane) ----
    const float bi  = bias[hh];
    const float bff = bias[1024 + hh];
    const float bo  = bias[2048 + hh];
    const float bc  = bias[3072 + hh];

    #pragma unroll
    for (int a = 0; a < 8; ++a) {
        const int rb = bm * 256 + wm * 128 + (a >> 2) * 64 + (a & 3) * 16 + ((l >> 4) * 4);
        #pragma unroll
        for (int j = 0; j < 4; ++j) {
            const int r = rb + j;
            float iv = acc[a][0][j] + bi;
            float fv = acc[a][1][j] + bff;
            float ov = acc[a][2][j] + bo;
            float gv = acc[a][3][j] + bc;
            float it = 1.f / (1.f + __expf(-iv));
            float ft = 1.f / (1.f + __expf(-fv));
            float ot = 1.f / (1.f + __expf(-ov));
            float gt = 1.f - 2.f / (1.f + __expf(2.f * gv));
            float cn = it * gt + ft * cv[a][j];
            float th = 1.f - 2.f / (1.f + __expf(2.f * cn));
            out[(size_t)r * H_DIM + hh] = ot * th;                          // h_new
            out[(size_t)B_ROWS * H_DIM + (size_t)r * H_DIM + hh] = cn;      // c
        }
    }
#undef PHASE
#undef STAGE
#undef GLDS
}

extern "C" void kernel_launch(void* const* d_in, const int* in_sizes, int n_in,
                              void* d_out, int out_size, void* d_ws, size_t ws_size,
                              hipStream_t stream) {
    const float* x  = (const float*)d_in[0];
    const float* h0 = (const float*)d_in[1];
    const float* c0 = (const float*)d_in[2];
    const float* Uw[4] = {(const float*)d_in[3],  (const float*)d_in[5],
                          (const float*)d_in[7],  (const float*)d_in[9]};
    const float* Ub[4] = {(const float*)d_in[4],  (const float*)d_in[6],
                          (const float*)d_in[8],  (const float*)d_in[10]};
    const float* Ww[4] = {(const float*)d_in[11], (const float*)d_in[13],
                          (const float*)d_in[15], (const float*)d_in[17]};
    const float* Wb[4] = {(const float*)d_in[12], (const float*)d_in[14],
                          (const float*)d_in[16], (const float*)d_in[18]};

    unsigned short* Ag = (unsigned short*)d_ws;                 // 48 MiB
    unsigned short* Bg = Ag + (size_t)B_ROWS * K_TOT;           // 12 MiB
    float* bias        = (float*)(Bg + (size_t)4096 * K_TOT);   // 16 KiB
    float* out         = (float*)d_out;

    cvt_all<<<15376, 256, 0, stream>>>(
        x, h0,
        Uw[0], Uw[1], Uw[2], Uw[3], Ww[0], Ww[1], Ww[2], Ww[3],
        Ub[0], Ub[1], Ub[2], Ub[3], Wb[0], Wb[1], Wb[2], Wb[3],
        Ag, Bg, bias);
    lstm_gemm<<<1024, 512, 0, stream>>>(Ag, Bg, bias, c0, out);
}